// Round 2
// baseline (339.597 us; speedup 1.0000x reference)
//
#include <hip/hip_runtime.h>
#include <stdint.h>

#define DI __device__ __forceinline__

using floatx4 = __attribute__((ext_vector_type(4))) float;
using short8  = __attribute__((ext_vector_type(8))) short;   // 8 bf16 in 4 VGPRs

DI uint16_t f2b(float f) {  // fp32 -> bf16 round-to-nearest-even
  uint32_t u = __float_as_uint(f);
  return (uint16_t)((u + 0x7FFFu + ((u >> 16) & 1u)) >> 16);
}

DI void async_cp16(const uint16_t* g, uint16_t* l) {
  // 16B per lane, LDS dest = wave-uniform base + lane*16 (no padding allowed)
  __builtin_amdgcn_global_load_lds(
      (const __attribute__((address_space(1))) void*)g,
      (__attribute__((address_space(3))) void*)l, 16, 0, 0);
}

// ---------------------------------------------------------------- X fp32->bf16
__global__ __launch_bounds__(256)
void cvt_bf16(const float* __restrict__ x, uint16_t* __restrict__ y) {
  long i = ((long)blockIdx.x * 256 + threadIdx.x) * 8;
  float4 a = *(const float4*)(x + i);
  float4 b = *(const float4*)(x + i + 4);
  union { uint16_t u[8]; uint4 v; } o;
  o.u[0] = f2b(a.x); o.u[1] = f2b(a.y); o.u[2] = f2b(a.z); o.u[3] = f2b(a.w);
  o.u[4] = f2b(b.x); o.u[5] = f2b(b.y); o.u[6] = f2b(b.z); o.u[7] = f2b(b.w);
  *(uint4*)(y + i) = o.v;
}

// ------------------------------------------------- T1[(ijkl)][b] = g0 x g1
__global__ __launch_bounds__(256)
void tt_t1(const float* __restrict__ g0, const float* __restrict__ g1,
           uint16_t* __restrict__ t1) {
  __shared__ float g0s[64 * 64];    // [row][a]  16KB
  __shared__ float g1s[64 * 128];   // [a][col]  32KB
  const int rowbase = blockIdx.x * 64;
  const int colbase = blockIdx.y * 128;
  const int t = threadIdx.x;

  for (int f = t; f < 4096; f += 256) g0s[f] = g0[rowbase * 64 + f];
  for (int f = t; f < 8192; f += 256) {
    int a = f >> 7, c = f & 127;
    g1s[f] = g1[(long)a * 16384 + colbase + c];
  }
  __syncthreads();

  const int tx = t & 31;
  const int ty = t >> 5;
  const int c0 = tx * 4;
  const int r0 = ty * 8;

  float acc[8][4];
  #pragma unroll
  for (int r = 0; r < 8; ++r)
    #pragma unroll
    for (int c = 0; c < 4; ++c) acc[r][c] = 0.f;

  for (int a4 = 0; a4 < 16; ++a4) {
    float g0r[8][4];
    #pragma unroll
    for (int r = 0; r < 8; ++r)
      *(float4*)&g0r[r][0] = *(const float4*)&g0s[(r0 + r) * 64 + a4 * 4];
    #pragma unroll
    for (int e = 0; e < 4; ++e) {
      float4 bv4 = *(const float4*)&g1s[(a4 * 4 + e) * 128 + c0];
      float bv[4] = {bv4.x, bv4.y, bv4.z, bv4.w};
      #pragma unroll
      for (int r = 0; r < 8; ++r)
        #pragma unroll
        for (int c = 0; c < 4; ++c)
          acc[r][c] += g0r[r][e] * bv[c];
    }
  }

  #pragma unroll
  for (int r = 0; r < 8; ++r) {
    ushort4 o;
    o.x = f2b(acc[r][0]); o.y = f2b(acc[r][1]);
    o.z = f2b(acc[r][2]); o.w = f2b(acc[r][3]);
    *(ushort4*)&t1[(long)(rowbase + r0 + r) * 16384 + colbase + c0] = o;
  }
}

// ------------------------------------------------- T1 (4096x1024) -> T1t (1024x4096)
__global__ __launch_bounds__(256)
void transpose_t1(const uint16_t* __restrict__ src, uint16_t* __restrict__ dst,
                  const float* __restrict__ g2, uint16_t* __restrict__ g2t) {
  __shared__ uint16_t tile[64][68];
  const int cb = blockIdx.x * 64;
  const int rb = blockIdx.y * 64;
  const int t = threadIdx.x;

  if (blockIdx.y == 0) {
    #pragma unroll
    for (int p = 0; p < 4; ++p) {
      int f = blockIdx.x * 1024 + p * 256 + t;
      int mn = f >> 6, b = f & 63;
      g2t[f] = f2b(g2[b * 256 + mn]);
    }
  }
  {
    const int c4 = (t & 15) * 4;
    const int r  = t >> 4;
    #pragma unroll
    for (int p = 0; p < 4; ++p) {
      int rr = r + p * 16;
      *(ushort4*)&tile[rr][c4] = *(const ushort4*)&src[(long)(rb + rr) * 1024 + cb + c4];
    }
  }
  __syncthreads();
  {
    const int r4 = (t & 15) * 4;
    const int c  = t >> 4;
    #pragma unroll
    for (int p = 0; p < 4; ++p) {
      int cc = c + p * 16;
      ushort4 o;
      o.x = tile[r4 + 0][cc]; o.y = tile[r4 + 1][cc];
      o.z = tile[r4 + 2][cc]; o.w = tile[r4 + 3][cc];
      *(ushort4*)&dst[(long)(cb + cc) * 4096 + rb + r4] = o;
    }
  }
}

// ------------------------------------------------- fused V=Xbf@T1 then out=V@g2+bias
// 8-phase-style schedule (T2+T3+T4+T5), BM=256 x BN=128, BK=64, 8 waves.
// grid 32x8 = 256 blocks = 1/CU. LDS: 3 rotating buffers (A 32KB + B 16KB each,
// 144KB dynamic), prefetch depth 2, boundary wait = s_waitcnt vmcnt(6) (never 0
// in main loop). XOR chunk-swizzle (involution, both-sides: pre-swizzled global
// source for global_load_lds + swizzled ds_read) kills the 128B-pitch bank
// conflict. 4 phases/K-tile, one C-quadrant each, MFMA wrapped in s_setprio.
// Phase 2: V-tile -> Vs[256][128] (same swizzle, aliases drained bufs) -> @g2t.
#define LDSA 16384   // shorts: A buffer 256x64
#define BUFS 24576   // shorts: A+B buffer (48KB)

DI short8 ld_frag(const uint16_t* buf, int row, int c) {
  // c = desired global k-chunk (0..7 of 8 shorts); LDS pos = c ^ (row&7)
  return *(const short8*)&buf[row * 64 + ((c ^ (row & 7)) << 3)];
}

DI void stageA2(const uint16_t* Ab, uint16_t* Abuf, int k0,
                int wave, int srow, int schunk8, int q0) {
  #pragma unroll
  for (int q = 0; q < 2; ++q) {
    const int rblk = wave * 4 + q0 + q;            // 8-row chunk, 1KB per issue
    async_cp16(Ab + (long)(rblk * 8 + srow) * 4096 + k0 + schunk8,
               Abuf + rblk * 512);
  }
}

DI void stageB2(const uint16_t* Bb, uint16_t* Bbuf, int k0,
                int wave, int srow, int schunk8) {
  #pragma unroll
  for (int q = 0; q < 2; ++q) {
    const int rblk = wave * 2 + q;
    async_cp16(Bb + (long)(rblk * 8 + srow) * 4096 + k0 + schunk8,
               Bbuf + rblk * 512);
  }
}

#define MFMA_QUAD(I0, J0)                                                    \
  _Pragma("unroll")                                                          \
  for (int i_ = 0; i_ < 2; ++i_)                                             \
    _Pragma("unroll")                                                        \
    for (int j_ = 0; j_ < 2; ++j_)                                           \
      _Pragma("unroll")                                                      \
      for (int ks_ = 0; ks_ < 2; ++ks_)                                      \
        acc[(I0) + i_][(J0) + j_] = __builtin_amdgcn_mfma_f32_16x16x32_bf16( \
            af[(I0) + i_][ks_], bg[(J0) + j_][ks_], acc[(I0) + i_][(J0) + j_], 0, 0, 0);

__global__ __launch_bounds__(512, 2)
void gemm_fused(const uint16_t* __restrict__ A,    // Xbf 8192x4096
                const uint16_t* __restrict__ Bt,   // T1t 1024x4096 (k-contig)
                const uint16_t* __restrict__ g2t,  // 256x64 (k=b contig)
                const float* __restrict__ bias,
                float* __restrict__ out) {
  extern __shared__ uint16_t lds[];   // 3*BUFS shorts = 144KB

  const int bm = blockIdx.x * 256;
  const int by = blockIdx.y;           // 128 lb-cols per block
  const int tid  = threadIdx.x;
  const int wave = tid >> 6;
  const int lane = tid & 63;
  const int wm = (wave >> 1) * 64;     // 4 M groups
  const int wn = (wave & 1) * 64;      // 2 N groups
  const int fr = lane & 15;            // fragment row
  const int ck = lane >> 4;            // fragment k-chunk base (0..3)

  // staging: each 1KB issue covers 8 rows x 8 chunks; lane l -> (row l>>3, pos l&7)
  // LDS pos p must hold global chunk p^(row&7)  =>  source chunk = (l&7)^(l>>3)
  const int srow    = lane >> 3;
  const int schunk8 = (((lane & 7) ^ srow) << 3);

  const uint16_t* Ab = A  + (long)bm * 4096;
  const uint16_t* Bb = Bt + (long)by * 128 * 4096;

  floatx4 acc[4][4];
  #pragma unroll
  for (int i = 0; i < 4; ++i)
    #pragma unroll
    for (int j = 0; j < 4; ++j)
      acc[i][j] = (floatx4){0.f, 0.f, 0.f, 0.f};

  uint16_t* pc = lds;               // tile t
  uint16_t* pn = lds + BUFS;        // tile t+1
  uint16_t* ps = lds + 2 * BUFS;    // staging target: tile t+2

  // ---- prologue: stage tiles 0 and 1 (6 issues each), wait oldest 6
  stageA2(Ab, pc, 0, wave, srow, schunk8, 0);
  stageA2(Ab, pc, 0, wave, srow, schunk8, 2);
  stageB2(Bb, pc + LDSA, 0, wave, srow, schunk8);
  stageA2(Ab, pn, 64, wave, srow, schunk8, 0);
  stageA2(Ab, pn, 64, wave, srow, schunk8, 2);
  stageB2(Bb, pn + LDSA, 64, wave, srow, schunk8);
  asm volatile("s_waitcnt vmcnt(6)" ::: "memory");
  __builtin_amdgcn_s_barrier();

  for (int t = 0; t < 64; ++t) {
    const int k2 = (t + 2) * 64;
    const bool pf = (t < 62);
    short8 af[4][2], bg[4][2];

    // ---- phase 0: read af[0..1], bg[0..1]; stage A chunks 0-1 of tile t+2
    #pragma unroll
    for (int x = 0; x < 2; ++x)
      #pragma unroll
      for (int ks = 0; ks < 2; ++ks) {
        af[x][ks] = ld_frag(pc,        wm + x * 16 + fr, ks * 4 + ck);
        bg[x][ks] = ld_frag(pc + LDSA, wn + x * 16 + fr, ks * 4 + ck);
      }
    if (pf) stageA2(Ab, ps, k2, wave, srow, schunk8, 0);
    __builtin_amdgcn_s_barrier();
    __builtin_amdgcn_s_setprio(1);
    MFMA_QUAD(0, 0);
    __builtin_amdgcn_s_setprio(0);
    __builtin_amdgcn_s_barrier();

    // ---- phase 1: read bg[2..3]; stage A chunks 2-3
    #pragma unroll
    for (int x = 2; x < 4; ++x)
      #pragma unroll
      for (int ks = 0; ks < 2; ++ks)
        bg[x][ks] = ld_frag(pc + LDSA, wn + x * 16 + fr, ks * 4 + ck);
    if (pf) stageA2(Ab, ps, k2, wave, srow, schunk8, 2);
    __builtin_amdgcn_s_barrier();
    __builtin_amdgcn_s_setprio(1);
    MFMA_QUAD(0, 2);
    __builtin_amdgcn_s_setprio(0);
    __builtin_amdgcn_s_barrier();

    // ---- phase 2: read af[2..3]; stage B
    #pragma unroll
    for (int x = 2; x < 4; ++x)
      #pragma unroll
      for (int ks = 0; ks < 2; ++ks)
        af[x][ks] = ld_frag(pc, wm + x * 16 + fr, ks * 4 + ck);
    if (pf) stageB2(Bb, ps + LDSA, k2, wave, srow, schunk8);
    __builtin_amdgcn_s_barrier();
    __builtin_amdgcn_s_setprio(1);
    MFMA_QUAD(2, 2);
    __builtin_amdgcn_s_setprio(0);
    __builtin_amdgcn_s_barrier();

    // ---- phase 3: no reads; boundary wait keeps 6 loads in flight (not 0)
    __builtin_amdgcn_s_setprio(1);
    MFMA_QUAD(2, 0);
    __builtin_amdgcn_s_setprio(0);
    if (t < 62) asm volatile("s_waitcnt vmcnt(6)" ::: "memory");
    else        asm volatile("s_waitcnt vmcnt(0)" ::: "memory");
    __builtin_amdgcn_s_barrier();

    uint16_t* tmp = pc; pc = pn; pn = ps; ps = tmp;
  }

  // ---- phase-1 epilogue: acc -> Vs[256][128] bf16, same XOR chunk swizzle
  const int colq = lane & 15;
  const int rowq = (lane >> 4) * 4;
  #pragma unroll
  for (int i = 0; i < 4; ++i)
    #pragma unroll
    for (int j = 0; j < 4; ++j)
      #pragma unroll
      for (int r = 0; r < 4; ++r) {
        const int row = wm + i * 16 + rowq + r;
        const int col = wn + j * 16 + colq;
        const int pos = ((col >> 3) & 8) | (((col >> 3) & 7) ^ (row & 7));
        lds[row * 128 + pos * 8 + (col & 7)] = f2b(acc[i][j][r]);
      }
  __syncthreads();

  // ---- phase 2: out[row][l*256+mn] = sum_b Vs[row][lsel*64+b] * g2t[mn][b] + bias
  const int lsel   = wave >> 2;            // which l (V col half)
  const int mnBase = (wave & 3) * 64;      // g2t row base
  const long ocol0 = (long)by * 512 + lsel * 256 + mnBase;
  const int fk = ck * 8;

  short8 bg2[4][2];
  #pragma unroll
  for (int jn = 0; jn < 4; ++jn)
    #pragma unroll
    for (int ks = 0; ks < 2; ++ks)
      bg2[jn][ks] = *(const short8*)&g2t[(mnBase + jn * 16 + fr) * 64 + ks * 32 + fk];

  float bvs[4];
  #pragma unroll
  for (int jn = 0; jn < 4; ++jn)
    bvs[jn] = bias[ocol0 + jn * 16 + colq];

  #pragma unroll
  for (int pass = 0; pass < 4; ++pass) {
    floatx4 acc2[4][4];
    #pragma unroll
    for (int im = 0; im < 4; ++im)
      #pragma unroll
      for (int jn = 0; jn < 4; ++jn)
        acc2[im][jn] = (floatx4){0.f, 0.f, 0.f, 0.f};

    short8 af2[4][2];
    #pragma unroll
    for (int im = 0; im < 4; ++im)
      #pragma unroll
      for (int ks = 0; ks < 2; ++ks) {
        const int row = pass * 64 + im * 16 + fr;
        af2[im][ks] = *(const short8*)&lds[row * 128 +
                        ((lsel * 8 + ((ks * 4 + ck) ^ (row & 7))) << 3)];
      }

    #pragma unroll
    for (int im = 0; im < 4; ++im)
      #pragma unroll
      for (int jn = 0; jn < 4; ++jn)
        #pragma unroll
        for (int ks = 0; ks < 2; ++ks)
          acc2[im][jn] = __builtin_amdgcn_mfma_f32_16x16x32_bf16(
              af2[im][ks], bg2[jn][ks], acc2[im][jn], 0, 0, 0);

    #pragma unroll
    for (int jn = 0; jn < 4; ++jn)
      #pragma unroll
      for (int im = 0; im < 4; ++im)
        #pragma unroll
        for (int r = 0; r < 4; ++r) {
          const int row = bm + pass * 64 + im * 16 + rowq + r;
          out[(long)row * 4096 + ocol0 + jn * 16 + colq] = acc2[im][jn][r] + bvs[jn];
        }
  }
}

// ---------------------------------------------------------------- launch
// ws layout (bytes): Xbf 64MB | T1 8MB | T1t 8MB | g2t 32KB  (~80MB)
static constexpr long XBF_OFF = 0;
static constexpr long T1_OFF  = 67108864;
static constexpr long T1T_OFF = 75497472;
static constexpr long G2T_OFF = 83886080;

extern "C" void kernel_launch(void* const* d_in, const int* in_sizes, int n_in,
                              void* d_out, int out_size, void* d_ws, size_t ws_size,
                              hipStream_t stream) {
  const float* x    = (const float*)d_in[0];
  const float* g0   = (const float*)d_in[1];
  const float* g1   = (const float*)d_in[2];
  const float* g2   = (const float*)d_in[3];
  const float* bias = (const float*)d_in[4];
  float* out = (float*)d_out;

  char* ws = (char*)d_ws;
  uint16_t* Xbf = (uint16_t*)(ws + XBF_OFF);
  uint16_t* T1  = (uint16_t*)(ws + T1_OFF);
  uint16_t* T1t = (uint16_t*)(ws + T1T_OFF);
  uint16_t* G2T = (uint16_t*)(ws + G2T_OFF);

  // allow 144KB dynamic LDS for gemm_fused (host-side, not stream-ordered)
  hipFuncSetAttribute((const void*)gemm_fused,
                      hipFuncAttributeMaxDynamicSharedMemorySize, 3 * BUFS * 2);

  // 1) X -> bf16
  cvt_bf16<<<16384, 256, 0, stream>>>(x, Xbf);
  // 2) T1[(ijk)][(lb)] bf16, 4096x1024 row-major
  tt_t1<<<dim3(4, 128), 256, 0, stream>>>(g0, g1, T1);
  // 3) T1t = T1^T (1024x4096, k-contig) + g2t side-job
  transpose_t1<<<dim3(16, 64), 256, 0, stream>>>(T1, T1t, g2, G2T);
  // 4) fused: V = Xbf @ T1 (8-phase, counted vmcnt) then out = V @ g2 + bias
  gemm_fused<<<dim3(32, 8), 512, 3 * BUFS * 2, stream>>>(Xbf, T1t, G2T, bias, out);
}